// Round 4
// baseline (70.403 us; speedup 1.0000x reference)
//
#include <hip/hip_runtime.h>
#include <hip/hip_bf16.h>

#define EPS 1e-7f
#define LDSW 260   // 256 + 4-float pad: rotates banks per row, keeps 16B alignment

typedef __attribute__((ext_vector_type(8))) short short8;
typedef __attribute__((ext_vector_type(4))) float f32x4;

// pack two floats to two bf16 (RNE) in one uint (low = first)
__device__ __forceinline__ unsigned pk(float a, float b) {
    __hip_bfloat162 h2 = __float22bfloat162_rn(make_float2(a, b));
    unsigned r; __builtin_memcpy(&r, &h2, 4); return r;
}

__device__ __forceinline__ short8 mk8(float4 f0, float4 f1) {
    uint4 u;
    u.x = pk(f0.x, f0.y); u.y = pk(f0.z, f0.w);
    u.z = pk(f1.x, f1.y); u.w = pk(f1.z, f1.w);
    short8 r; __builtin_memcpy(&r, &u, 16); return r;
}

// ---------------------------------------------------------------------------
// One fused kernel. Block b: 16 batch rows x all 256 m.
//   - stage ymc = y - c (fp32) in LDS, coalesced
//   - 8 waves; wave w owns m-tiles {2w, 2w+1}
//   - per s-step: build A-frag af from LDS ymc, B-frags bf0/bf1 from global A
//     (fp32 -> bf16 on the fly, L2-hot), c-frag cf from global c;
//     4 MFMAs: dots A(y-c) for both tiles + Ac for both tiles
//   - cand/min epilogue (shuffle + tiny LDS), alpha block-local
//   - z = c + alpha * ymc from LDS, coalesced
// ---------------------------------------------------------------------------
__global__ __launch_bounds__(512, 1)
void fused_kernel(const float* __restrict__ y, const float* __restrict__ A,
                  const float* __restrict__ bb, const float* __restrict__ c,
                  float* __restrict__ z)
{
    __shared__ float ymc[16][LDSW];
    __shared__ float red[8][16];
    __shared__ float alphas[16];

    const int t    = threadIdx.x;
    const int w    = t >> 6;
    const int lane = t & 63;
    const int lr   = lane & 15;   // B-frag col (m) / A-frag row (batch)
    const int lg   = lane >> 4;   // k-group
    const int b0   = blockIdx.x * 16;

    const float4* y4  = (const float4*)y;
    const float4* c4g = (const float4*)c;
    float4* z4 = (float4*)z;

    // stage ymc = y - c (coalesced float4; row stride 260 floats = 1040 B, 16B-aligned)
    #pragma unroll
    for (int k = 0; k < 2; ++k) {
        int pos = t + k * 512;
        int row = pos >> 6, col4 = pos & 63;
        float4 yv = y4[(size_t)(b0 + row) * 64 + col4];
        float4 cv = c4g[col4];
        float4 r;
        r.x = yv.x - cv.x; r.y = yv.y - cv.y;
        r.z = yv.z - cv.z; r.w = yv.w - cv.w;
        *(float4*)&ymc[row][col4 * 4] = r;
    }
    __syncthreads();

    f32x4 acc0  = {0.f,0.f,0.f,0.f};   // A(y-c), m-tile 2w
    f32x4 acc1  = {0.f,0.f,0.f,0.f};   // A(y-c), m-tile 2w+1
    f32x4 accc0 = {0.f,0.f,0.f,0.f};   // A·c,    m-tile 2w
    f32x4 accc1 = {0.f,0.f,0.f,0.f};   // A·c,    m-tile 2w+1

    const int MT0 = 2 * w, MT1 = MT0 + 1;
    const float* a0 = A + (size_t)(MT0 * 16 + lr) * 256;
    const float* a1 = A + (size_t)(MT1 * 16 + lr) * 256;

    #pragma unroll
    for (int s = 0; s < 8; ++s) {
        const int col = 32 * s + 8 * lg;
        // A-frag from LDS (balanced banks via +4 pad)
        float4 yv0 = *(const float4*)&ymc[lr][col];
        float4 yv1 = *(const float4*)&ymc[lr][col + 4];
        short8 af = mk8(yv0, yv1);
        // B-frags from global A (16 rows x 128B lines per instr, L2-hot)
        float4 a00 = *(const float4*)(a0 + col);
        float4 a01 = *(const float4*)(a0 + col + 4);
        float4 a10 = *(const float4*)(a1 + col);
        float4 a11 = *(const float4*)(a1 + col + 4);
        short8 bf0 = mk8(a00, a01);
        short8 bf1 = mk8(a10, a11);
        // c-frag: every A-operand row = c (lane value depends only on lg,s)
        float4 cv0 = *(const float4*)(c + col);
        float4 cv1 = *(const float4*)(c + col + 4);
        short8 cf = mk8(cv0, cv1);

        acc0  = __builtin_amdgcn_mfma_f32_16x16x32_bf16(af, bf0, acc0,  0, 0, 0);
        acc1  = __builtin_amdgcn_mfma_f32_16x16x32_bf16(af, bf1, acc1,  0, 0, 0);
        accc0 = __builtin_amdgcn_mfma_f32_16x16x32_bf16(cf, bf0, accc0, 0, 0, 0);
        accc1 = __builtin_amdgcn_mfma_f32_16x16x32_bf16(cf, bf1, accc1, 0, 0, 0);
    }

    // epilogue: cand + min over m (C/D: col m = MT*16+lr, batch row = 4*lg+q)
    const int m0 = MT0 * 16 + lr;
    const int m1 = MT1 * 16 + lr;
    const float bm0 = bb[m0] - accc0[0];
    const float bm1 = bb[m1] - accc1[0];

    float cmin[4];
    #pragma unroll
    for (int q = 0; q < 4; ++q) {
        float ip0 = bm0 / (acc0[q] + EPS);
        float ip1 = bm1 / (acc1[q] + EPS);
        float c0 = (ip0 > 1.f || ip0 < 0.f) ? 2.f : ip0;
        float c1 = (ip1 > 1.f || ip1 < 0.f) ? 2.f : ip1;
        cmin[q] = fminf(c0, c1);
    }
    #pragma unroll
    for (int q = 0; q < 4; ++q) {
        float v = cmin[q];
        v = fminf(v, __shfl_xor(v, 1));
        v = fminf(v, __shfl_xor(v, 2));
        v = fminf(v, __shfl_xor(v, 4));
        v = fminf(v, __shfl_xor(v, 8));
        cmin[q] = v;
    }
    if (lr == 0) {
        #pragma unroll
        for (int q = 0; q < 4; ++q) red[w][lg * 4 + q] = cmin[q];
    }
    __syncthreads();

    if (t < 16) {
        float a = red[0][t];
        #pragma unroll
        for (int i = 1; i < 8; ++i) a = fminf(a, red[i][t]);
        alphas[t] = fminf(a, 1.0f);   // alpha > 1 -> 1
    }
    __syncthreads();

    // z = c + alpha * (y - c) from LDS, coalesced float4 stores
    #pragma unroll
    for (int k = 0; k < 2; ++k) {
        int pos = t + k * 512;
        int row = pos >> 6, col4 = pos & 63;
        float al = alphas[row];
        float4 m  = *(const float4*)&ymc[row][col4 * 4];
        float4 cv = c4g[col4];
        float4 o;
        o.x = fmaf(al, m.x, cv.x);
        o.y = fmaf(al, m.y, cv.y);
        o.z = fmaf(al, m.z, cv.z);
        o.w = fmaf(al, m.w, cv.w);
        z4[(size_t)(b0 + row) * 64 + col4] = o;
    }
}

extern "C" void kernel_launch(void* const* d_in, const int* in_sizes, int n_in,
                              void* d_out, int out_size, void* d_ws, size_t ws_size,
                              hipStream_t stream) {
    const float* y = (const float*)d_in[0];
    const float* A = (const float*)d_in[1];
    const float* b = (const float*)d_in[2];
    const float* c = (const float*)d_in[3];
    float* z = (float*)d_out;

    const int B = in_sizes[0] / 256;    // 4096
    fused_kernel<<<B / 16, 512, 0, stream>>>(y, A, b, c, z);
}